// Round 4
// baseline (580.505 us; speedup 1.0000x reference)
//
#include <hip/hip_runtime.h>

#define NN 50000
#define KSEQ 20
#define HN_OFF 6400000   // N*128
#define CN_OFF 12800000  // 2*N*128

using short8 = __attribute__((ext_vector_type(8))) short;
using f32x4  = __attribute__((ext_vector_type(4))) float;

__device__ __forceinline__ unsigned short f2bf(float f) {
    unsigned int u = __float_as_uint(f);
    return (unsigned short)((u + 0x7FFFu + ((u >> 16) & 1u)) >> 16);  // RNE
}
__device__ __forceinline__ float exp2x(float x) { float r; asm("v_exp_f32 %0, %1" : "=v"(r) : "v"(x)); return r; }
__device__ __forceinline__ float rcpx(float x)  { float r; asm("v_rcp_f32 %0, %1" : "=v"(r) : "v"(x)); return r; }

#define L2E 1.4426950408889634f
__device__ __forceinline__ float sigx(float x)  { return rcpx(1.f + exp2x(-L2E * x)); }
__device__ __forceinline__ float tanhx(float x) { return fmaf(-2.f, rcpx(1.f + exp2x((2.f * L2E) * x)), 1.f); }

// ---- prep: bf16 weight packs (+transposes) and bias sum ----
__global__ void prep_kernel(const float* __restrict__ Wp, const float* __restrict__ W,
                            const float* __restrict__ Wih, const float* __restrict__ Whh,
                            const float* __restrict__ bih, const float* __restrict__ bhh,
                            unsigned short* __restrict__ Wih_b, unsigned short* __restrict__ Whh_b,
                            unsigned short* __restrict__ Wpt, unsigned short* __restrict__ Wtt,
                            float* __restrict__ bsum) {
    int tid = blockIdx.x * blockDim.x + threadIdx.x;
    if (tid < 65536) { Wih_b[tid] = f2bf(Wih[tid]); return; }
    tid -= 65536;
    if (tid < 65536) { Whh_b[tid] = f2bf(Whh[tid]); return; }
    tid -= 65536;
    if (tid < 32768) { int j = tid >> 8, k = tid & 255; Wpt[tid] = f2bf(Wp[k * 128 + j]); return; }
    tid -= 32768;
    if (tid < 32768) { int j = tid >> 8, k = tid & 255; Wtt[tid] = f2bf(W[k * 128 + j]); return; }
    tid -= 32768;
    if (tid < 512) { bsum[tid] = bih[tid] + bhh[tid]; }
}

// ---- K1: hp = bf16(h @ W_past), 32 rows/block, 8 waves (16 cols each) ----
__global__ __launch_bounds__(512, 2) void hp_kernel(const float* __restrict__ h,
                                                    const unsigned short* __restrict__ Wpt,
                                                    unsigned short* __restrict__ hp_bf) {
    __shared__ __align__(16) unsigned char smem[32 * 512];
    const int tid = threadIdx.x;
    const int w = tid >> 6, l = tid & 63;
    const int l15 = l & 15, lq = l >> 4;
    const int base = blockIdx.x * 32;

#pragma unroll
    for (int i = 0; i < 4; ++i) {
        int chunk = tid + 512 * i;
        int row = chunk >> 6, kc = chunk & 63;
        int grow = base + row;
        float4 v = make_float4(0.f, 0.f, 0.f, 0.f);
        if (grow < NN) v = *(const float4*)(h + (size_t)grow * 256 + kc * 4);
        ushort4 bv = make_ushort4(f2bf(v.x), f2bf(v.y), f2bf(v.z), f2bf(v.w));
        int off = (row * 512 + kc * 8) ^ ((row & 7) << 4);
        *(ushort4*)(smem + off) = bv;
    }
    __syncthreads();

    const int jb = w * 16 + l15;
    short8 bf[8];
#pragma unroll
    for (int kt = 0; kt < 8; ++kt)
        bf[kt] = *(const short8*)((const unsigned char*)Wpt + jb * 512 + kt * 64 + lq * 16);

    f32x4 acc[2];
    acc[0] = (f32x4){0.f, 0.f, 0.f, 0.f};
    acc[1] = (f32x4){0.f, 0.f, 0.f, 0.f};
#pragma unroll
    for (int kt = 0; kt < 8; ++kt) {
#pragma unroll
        for (int rt = 0; rt < 2; ++rt) {
            int arow = rt * 16 + l15;
            int off = (arow * 512 + kt * 64 + lq * 16) ^ ((arow & 7) << 4);
            short8 a = *(const short8*)(smem + off);
            acc[rt] = __builtin_amdgcn_mfma_f32_16x16x32_bf16(a, bf[kt], acc[rt], 0, 0, 0);
        }
    }
#pragma unroll
    for (int rt = 0; rt < 2; ++rt)
#pragma unroll
        for (int r = 0; r < 4; ++r) {
            int row = rt * 16 + lq * 4 + r;
            int grow = base + row;
            if (grow < NN) hp_bf[(size_t)grow * 128 + w * 16 + l15] = f2bf(acc[rt][r]);
        }
}

// ---- K2: cross-step pipelined LSTM + output GEMM. 32 rows/block, 16 waves.
// p0 waves (0-7): gates (i, g) for 16 cols; p1 waves (8-15): gates (f, o).
// p0 computes a = sigma(i)*tanh(g) locally -> 1 float exchange per element.
// x-GEMM of step t+1 overlaps step t's activation VALU; h-GEMM of t+1 overlaps
// the gather/stage of x_{t+2}.
// LDS: xbuf0 @0 (8KB), xbuf1 @8192, hbuf @16384 (8KB), sbuf @24576 (32 rows x 520B)
#define HBUF 16384
#define SBUF 24576
#define SSTR 520

__global__ __launch_bounds__(1024, 4) void lstm_kernel(const unsigned short* __restrict__ hp_bf,
                                                       const int* __restrict__ agg,
                                                       const unsigned short* __restrict__ Wih_b,
                                                       const unsigned short* __restrict__ Whh_b,
                                                       const unsigned short* __restrict__ Wtt,
                                                       const float* __restrict__ bsum,
                                                       float* __restrict__ out) {
    __shared__ __align__(16) unsigned char lds[SBUF + 32 * SSTR];
    const int tid = threadIdx.x;
    const int w = tid >> 6, l = tid & 63;
    const int p = w >> 3, b = w & 7;
    const int l15 = l & 15, lq = l >> 4;
    const int base = blockIdx.x * 32;
    const int colj = b * 16 + l15;

    // B fragments: gates (p*128+colj, +256) x 8 k-tiles (0..3: W_ih/x, 4..7: W_hh/h)
    short8 bw[2][8];
    const int jA = p * 128 + colj;
#pragma unroll
    for (int kt = 0; kt < 4; ++kt) {
        bw[0][kt]     = *(const short8*)((const unsigned char*)Wih_b + jA * 256 + kt * 64 + lq * 16);
        bw[1][kt]     = *(const short8*)((const unsigned char*)Wih_b + (jA + 256) * 256 + kt * 64 + lq * 16);
        bw[0][kt + 4] = *(const short8*)((const unsigned char*)Whh_b + jA * 256 + kt * 64 + lq * 16);
        bw[1][kt + 4] = *(const short8*)((const unsigned char*)Whh_b + (jA + 256) * 256 + kt * 64 + lq * 16);
    }
    const float bi0 = bsum[jA];
    const float bi1 = bsum[jA + 256];

    // A-frag base LDS offset (rt=0, kt=0); rt adds 4096, kt XORs kt<<6
    const int off0 = (l15 * 256 + lq * 16) ^ ((l15 & 7) << 4);
    // sbuf base for (row = lq*4, col = colj); (rt,r) add rt*16*SSTR + r*SSTR
    const int sb0 = SBUF + lq * 4 * SSTR + colj * 4;
    // hbuf write base (row = lq*4, col = colj)
    const int hb0 = HBUF + lq * 4 * 256 + colj * 2;
    const int hswz = (lq & 1) << 6;

    // staging (p0 waves gather + stage x)
    const int srow = b * 4 + lq;
    int sgrow = base + srow; if (sgrow >= NN) sgrow = NN - 1;
    const int* aggrow = agg + (size_t)sgrow * KSEQ;
    const int xw_off = (srow * 256 + l15 * 16) ^ ((srow & 7) << 4);

    f32x4 cst[2];
    cst[0] = (f32x4){0.f, 0.f, 0.f, 0.f};
    cst[1] = (f32x4){0.f, 0.f, 0.f, 0.f};

    f32x4 accA[2][2], accB[2][2];
    int gidx = 0;
    if (p == 0) {
        int i0 = aggrow[0], i1 = aggrow[1];
        uint4 v0 = *(const uint4*)((const unsigned char*)hp_bf + (size_t)i0 * 256 + l15 * 16);
        uint4 v1 = *(const uint4*)((const unsigned char*)hp_bf + (size_t)i1 * 256 + l15 * 16);
        *(uint4*)(lds + xw_off) = v0;          // x_0 -> xbuf0
        *(uint4*)(lds + 8192 + xw_off) = v1;   // x_1 -> xbuf1
        gidx = aggrow[2];                      // index for gather at t=0 (x_2)
    }
    __syncthreads();

    // accA = bias + x_0 * Wx   (h_0 = 0)
#pragma unroll
    for (int rt = 0; rt < 2; ++rt) {
        accA[0][rt] = (f32x4){bi0, bi0, bi0, bi0};
        accA[1][rt] = (f32x4){bi1, bi1, bi1, bi1};
    }
#pragma unroll
    for (int kt = 0; kt < 4; ++kt) {
        const int xo = off0 ^ (kt << 6);
#pragma unroll
        for (int rt = 0; rt < 2; ++rt) {
            short8 a = *(const short8*)(lds + rt * 4096 + xo);
            accA[0][rt] = __builtin_amdgcn_mfma_f32_16x16x32_bf16(a, bw[0][kt], accA[0][rt], 0, 0, 0);
            accA[1][rt] = __builtin_amdgcn_mfma_f32_16x16x32_bf16(a, bw[1][kt], accA[1][rt], 0, 0, 0);
        }
    }

#pragma unroll 1
    for (int t = 0; t < KSEQ; ++t) {
        const bool xnext = (t < KSEQ - 1);
        const int xrd = ((t + 1) & 1) << 13;   // xbuf parity for x_{t+1}
        const int xwr = (t & 1) << 13;         // xbuf parity for x_{t+2}

        uint4 vnext;
        if (p == 0 && xnext) {
            vnext = *(const uint4*)((const unsigned char*)hp_bf + (size_t)gidx * 256 + l15 * 16);
            gidx = (t <= 16) ? aggrow[t + 3] : sgrow;   // prefetch next gather index
        }

        // activation VALU on accA (step t) overlapped with x-GEMM of t+1
        if (p == 0) {
#pragma unroll
            for (int rt = 0; rt < 2; ++rt)
#pragma unroll
                for (int r = 0; r < 4; ++r) {
                    float a = sigx(accA[0][rt][r]) * tanhx(accA[1][rt][r]);
                    *(float*)(lds + sb0 + rt * 16 * SSTR + r * SSTR) = a;
                }
        } else {
#pragma unroll
            for (int rt = 0; rt < 2; ++rt)
#pragma unroll
                for (int r = 0; r < 4; ++r) {
                    accA[0][rt][r] = sigx(accA[0][rt][r]);   // sigma(f)
                    accA[1][rt][r] = sigx(accA[1][rt][r]);   // sigma(o)
                }
        }
        if (xnext) {
#pragma unroll
            for (int rt = 0; rt < 2; ++rt) {
                accB[0][rt] = (f32x4){bi0, bi0, bi0, bi0};
                accB[1][rt] = (f32x4){bi1, bi1, bi1, bi1};
            }
#pragma unroll
            for (int kt = 0; kt < 4; ++kt) {
                const int xo = xrd + (off0 ^ (kt << 6));
#pragma unroll
                for (int rt = 0; rt < 2; ++rt) {
                    short8 a = *(const short8*)(lds + rt * 4096 + xo);
                    accB[0][rt] = __builtin_amdgcn_mfma_f32_16x16x32_bf16(a, bw[0][kt], accB[0][rt], 0, 0, 0);
                    accB[1][rt] = __builtin_amdgcn_mfma_f32_16x16x32_bf16(a, bw[1][kt], accB[1][rt], 0, 0, 0);
                }
            }
        }
        __syncthreads();  // B1: sbuf(a) visible; xbuf[xrd] reads done

        if (p == 1) {
            // c update + h_{t+1}; write h to hbuf (bf16)
#pragma unroll
            for (int rt = 0; rt < 2; ++rt)
#pragma unroll
                for (int r = 0; r < 4; ++r) {
                    float a = *(const float*)(lds + sb0 + rt * 16 * SSTR + r * SSTR);
                    float c = fmaf(accA[0][rt][r], cst[rt][r], a);
                    cst[rt][r] = c;
                    float hv = accA[1][rt][r] * tanhx(c);
                    unsigned pk;
                    asm("v_cvt_pk_bf16_f32 %0, %1, %2" : "=v"(pk) : "v"(hv), "v"(hv));
                    int hoff = (hb0 + rt * 4096 + r * 256) ^ (hswz | (r << 4));
                    *(unsigned short*)(lds + hoff) = (unsigned short)pk;
                    if (t == KSEQ - 1) {
                        int row = rt * 16 + lq * 4 + r;
                        int grow = base + row;
                        if (grow < NN) {
                            out[HN_OFF + (size_t)grow * 128 + colj] = hv;
                            out[CN_OFF + (size_t)grow * 128 + colj] = c;
                        }
                    }
                }
        }
        __syncthreads();  // B2: hbuf = h_{t+1} ready

        if (xnext) {
            // h-GEMM of step t+1; p0 stages x_{t+2} (or own hp at t=18)
#pragma unroll
            for (int kt = 0; kt < 4; ++kt) {
                const int ho = HBUF + (off0 ^ (kt << 6));
#pragma unroll
                for (int rt = 0; rt < 2; ++rt) {
                    short8 a = *(const short8*)(lds + rt * 4096 + ho);
                    accB[0][rt] = __builtin_amdgcn_mfma_f32_16x16x32_bf16(a, bw[0][kt + 4], accB[0][rt], 0, 0, 0);
                    accB[1][rt] = __builtin_amdgcn_mfma_f32_16x16x32_bf16(a, bw[1][kt + 4], accB[1][rt], 0, 0, 0);
                }
            }
            if (p == 0) *(uint4*)(lds + xwr + xw_off) = vnext;
            // rotate accA <- accB
#pragma unroll
            for (int g = 0; g < 2; ++g)
#pragma unroll
                for (int rt = 0; rt < 2; ++rt)
                    accA[g][rt] = accB[g][rt];
        }
    }
    // here: hbuf = h_20; xbuf0 = own hp rows (staged at t=18)

    // epilogue: out = elu([hp | h_n] @ W); all 16 waves, row-half rt = p
    short8 bo[8];
#pragma unroll
    for (int kt = 0; kt < 8; ++kt)
        bo[kt] = *(const short8*)((const unsigned char*)Wtt + colj * 512 + kt * 64 + lq * 16);

    f32x4 a2 = (f32x4){0.f, 0.f, 0.f, 0.f};
    const int ebase = p * 4096;
#pragma unroll
    for (int kt = 0; kt < 4; ++kt) {
        short8 a = *(const short8*)(lds + ebase + (off0 ^ (kt << 6)));           // hp (xbuf0)
        a2 = __builtin_amdgcn_mfma_f32_16x16x32_bf16(a, bo[kt], a2, 0, 0, 0);
    }
#pragma unroll
    for (int kt = 0; kt < 4; ++kt) {
        short8 a = *(const short8*)(lds + HBUF + ebase + (off0 ^ (kt << 6)));    // h_n (hbuf)
        a2 = __builtin_amdgcn_mfma_f32_16x16x32_bf16(a, bo[kt + 4], a2, 0, 0, 0);
    }
#pragma unroll
    for (int r = 0; r < 4; ++r) {
        int row = p * 16 + lq * 4 + r;
        int grow = base + row;
        if (grow < NN) {
            float v = a2[r];
            out[(size_t)grow * 128 + colj] = (v > 0.f) ? v : (exp2x(L2E * v) - 1.f);
        }
    }
}

extern "C" void kernel_launch(void* const* d_in, const int* in_sizes, int n_in,
                              void* d_out, int out_size, void* d_ws, size_t ws_size,
                              hipStream_t stream) {
    (void)in_sizes; (void)n_in; (void)out_size; (void)ws_size;
    const float* h   = (const float*)d_in[0];
    const int*   agg = (const int*)d_in[1];
    const float* Wp  = (const float*)d_in[2];
    const float* W   = (const float*)d_in[3];
    const float* Wih = (const float*)d_in[4];
    const float* Whh = (const float*)d_in[5];
    const float* bih = (const float*)d_in[6];
    const float* bhh = (const float*)d_in[7];
    float* out = (float*)d_out;

    unsigned short* hp_bf = (unsigned short*)d_ws;       // 50000*128 bf16
    unsigned short* Wih_b = hp_bf + 6400000;             // 512*128
    unsigned short* Whh_b = Wih_b + 65536;               // 512*128
    unsigned short* Wpt   = Whh_b + 65536;               // 128*256 (W_past^T)
    unsigned short* Wtt   = Wpt + 32768;                 // 128*256 (W^T)
    float*          bsum  = (float*)(Wtt + 32768);       // 512

    prep_kernel<<<771, 256, 0, stream>>>(Wp, W, Wih, Whh, bih, bhh, Wih_b, Whh_b, Wpt, Wtt, bsum);
    hp_kernel<<<1563, 512, 0, stream>>>(h, Wpt, hp_bf);
    lstm_kernel<<<1563, 1024, 0, stream>>>(hp_bf, agg, Wih_b, Whh_b, Wtt, bsum, out);
}

// Round 5
// 566.027 us; speedup vs baseline: 1.0256x; 1.0256x over previous
//
#include <hip/hip_runtime.h>

#define NN 50000
#define KSEQ 20
#define HN_OFF 6400000   // N*128
#define CN_OFF 12800000  // 2*N*128

using short8 = __attribute__((ext_vector_type(8))) short;
using f32x4  = __attribute__((ext_vector_type(4))) float;

__device__ __forceinline__ unsigned short f2bf(float f) {
    unsigned int u = __float_as_uint(f);
    return (unsigned short)((u + 0x7FFFu + ((u >> 16) & 1u)) >> 16);  // RNE
}
__device__ __forceinline__ float exp2x(float x) { float r; asm("v_exp_f32 %0, %1" : "=v"(r) : "v"(x)); return r; }
__device__ __forceinline__ float rcpx(float x)  { float r; asm("v_rcp_f32 %0, %1" : "=v"(r) : "v"(x)); return r; }

#define L2E 1.4426950408889634f
__device__ __forceinline__ float sigx(float x)  { return rcpx(1.f + exp2x(-L2E * x)); }
__device__ __forceinline__ float tanhx(float x) { return fmaf(-2.f, rcpx(1.f + exp2x((2.f * L2E) * x)), 1.f); }

// ---- prep: bf16 weight packs (+transposes) and bias sum ----
__global__ void prep_kernel(const float* __restrict__ Wp, const float* __restrict__ W,
                            const float* __restrict__ Wih, const float* __restrict__ Whh,
                            const float* __restrict__ bih, const float* __restrict__ bhh,
                            unsigned short* __restrict__ Wih_b, unsigned short* __restrict__ Whh_b,
                            unsigned short* __restrict__ Wpt, unsigned short* __restrict__ Wtt,
                            float* __restrict__ bsum) {
    int tid = blockIdx.x * blockDim.x + threadIdx.x;
    if (tid < 65536) { Wih_b[tid] = f2bf(Wih[tid]); return; }
    tid -= 65536;
    if (tid < 65536) { Whh_b[tid] = f2bf(Whh[tid]); return; }
    tid -= 65536;
    if (tid < 32768) { int j = tid >> 8, k = tid & 255; Wpt[tid] = f2bf(Wp[k * 128 + j]); return; }
    tid -= 32768;
    if (tid < 32768) { int j = tid >> 8, k = tid & 255; Wtt[tid] = f2bf(W[k * 128 + j]); return; }
    tid -= 32768;
    if (tid < 512) { bsum[tid] = bih[tid] + bhh[tid]; }
}

// ---- K1: hp = bf16(h @ W_past), 32 rows/block, 8 waves (16 cols each) ----
__global__ __launch_bounds__(512, 2) void hp_kernel(const float* __restrict__ h,
                                                    const unsigned short* __restrict__ Wpt,
                                                    unsigned short* __restrict__ hp_bf) {
    __shared__ __align__(16) unsigned char smem[32 * 512];
    const int tid = threadIdx.x;
    const int w = tid >> 6, l = tid & 63;
    const int l15 = l & 15, lq = l >> 4;
    const int base = blockIdx.x * 32;

#pragma unroll
    for (int i = 0; i < 4; ++i) {
        int chunk = tid + 512 * i;
        int row = chunk >> 6, kc = chunk & 63;
        int grow = base + row;
        float4 v = make_float4(0.f, 0.f, 0.f, 0.f);
        if (grow < NN) v = *(const float4*)(h + (size_t)grow * 256 + kc * 4);
        ushort4 bv = make_ushort4(f2bf(v.x), f2bf(v.y), f2bf(v.z), f2bf(v.w));
        int off = (row * 512 + kc * 8) ^ ((row & 7) << 4);
        *(ushort4*)(smem + off) = bv;
    }
    __syncthreads();

    const int jb = w * 16 + l15;
    short8 bf[8];
#pragma unroll
    for (int kt = 0; kt < 8; ++kt)
        bf[kt] = *(const short8*)((const unsigned char*)Wpt + jb * 512 + kt * 64 + lq * 16);

    f32x4 acc[2];
    acc[0] = (f32x4){0.f, 0.f, 0.f, 0.f};
    acc[1] = (f32x4){0.f, 0.f, 0.f, 0.f};
#pragma unroll
    for (int kt = 0; kt < 8; ++kt) {
#pragma unroll
        for (int rt = 0; rt < 2; ++rt) {
            int arow = rt * 16 + l15;
            int off = (arow * 512 + kt * 64 + lq * 16) ^ ((arow & 7) << 4);
            short8 a = *(const short8*)(smem + off);
            acc[rt] = __builtin_amdgcn_mfma_f32_16x16x32_bf16(a, bf[kt], acc[rt], 0, 0, 0);
        }
    }
#pragma unroll
    for (int rt = 0; rt < 2; ++rt)
#pragma unroll
        for (int r = 0; r < 4; ++r) {
            int row = rt * 16 + lq * 4 + r;
            int grow = base + row;
            if (grow < NN) hp_bf[(size_t)grow * 128 + w * 16 + l15] = f2bf(acc[rt][r]);
        }
}

// ---- K2: two-interval pipelined LSTM + output GEMM. 32 rows/block, 16 waves.
// p0 waves (0-7): gates (i, g); p1 waves (8-15): gates (f, o); 16 cols each.
// Interval A(t): gather issue | h-GEMM(t) into acc | acts (p0: a=sig(i)tanh(g)->sbuf;
//                p1: cst*=sig(f), so=sig(o))                                  | B2
// Interval B(t): x-GEMM(t+1) into reborn acc | p1: c=cst+a, h->hbuf | p0: stage x | B1
// LDS (40KB): xbuf0 @0, xbuf1 @8192, hbuf @16384, sbuf @24576 (slab-per-(rt,r,b), 2-way max)
#define HBUF 16384
#define SBUF 24576

__global__ __launch_bounds__(1024, 4) void lstm_kernel(const unsigned short* __restrict__ hp_bf,
                                                       const int* __restrict__ agg,
                                                       const unsigned short* __restrict__ Wih_b,
                                                       const unsigned short* __restrict__ Whh_b,
                                                       const unsigned short* __restrict__ Wtt,
                                                       const float* __restrict__ bsum,
                                                       float* __restrict__ out) {
    __shared__ __align__(16) unsigned char lds[40960];
    const int tid = threadIdx.x;
    const int w = tid >> 6, l = tid & 63;
    const int p = w >> 3, b = w & 7;
    const int l15 = l & 15, lq = l >> 4;
    const int base = blockIdx.x * 32;
    const int colj = b * 16 + l15;

    // B fragments: gates (p0: i@0,g@256 ; p1: f@128,o@384), kt 0-3: W_ih, 4-7: W_hh
    short8 bw[2][8];
    const int jA = p * 128 + colj;
#pragma unroll
    for (int kt = 0; kt < 4; ++kt) {
        bw[0][kt]     = *(const short8*)((const unsigned char*)Wih_b + jA * 256 + kt * 64 + lq * 16);
        bw[1][kt]     = *(const short8*)((const unsigned char*)Wih_b + (jA + 256) * 256 + kt * 64 + lq * 16);
        bw[0][kt + 4] = *(const short8*)((const unsigned char*)Whh_b + jA * 256 + kt * 64 + lq * 16);
        bw[1][kt + 4] = *(const short8*)((const unsigned char*)Whh_b + (jA + 256) * 256 + kt * 64 + lq * 16);
    }
    const float bi0 = bsum[jA];
    const float bi1 = bsum[jA + 256];

    // A-frag base LDS offset (rt=0, kt=0); rt adds 4096, kt XORs kt<<6
    const int off0 = (l15 * 256 + lq * 16) ^ ((l15 & 7) << 4);
    // sbuf: slab-per-(rt,r,b): addr = SBUF + rt*8192 + r*2048 + b*256 + lq*64 + l15*4 (2-way max)
    const int sb0 = SBUF + b * 256 + lq * 64 + l15 * 4;
    // hbuf write base (row = lq*4 + r + rt*16, col = colj)
    const int hb0 = HBUF + lq * 1024 + colj * 2;
    const int hswz = (lq & 1) << 6;

    // staging (p0 waves gather + stage x): lane handles (row srow, 16B chunk l15)
    const int srow = b * 4 + lq;
    int sgrow = base + srow; if (sgrow >= NN) sgrow = NN - 1;
    const int* aggrow = agg + (size_t)sgrow * KSEQ;
    const int xw_off = (srow * 256 + l15 * 16) ^ ((srow & 7) << 4);

    f32x4 cst[2];
    cst[0] = (f32x4){0.f, 0.f, 0.f, 0.f};
    cst[1] = (f32x4){0.f, 0.f, 0.f, 0.f};
    float so_[2][4];

    f32x4 acc[2][2];
    int gidx = 0;
    if (p == 0) {
        int i0 = aggrow[0], i1 = aggrow[1];
        uint4 v0 = *(const uint4*)((const unsigned char*)hp_bf + (size_t)i0 * 256 + l15 * 16);
        uint4 v1 = *(const uint4*)((const unsigned char*)hp_bf + (size_t)i1 * 256 + l15 * 16);
        *(uint4*)(lds + xw_off) = v0;          // x_0 -> xbuf0
        *(uint4*)(lds + 8192 + xw_off) = v1;   // x_1 -> xbuf1
        gidx = aggrow[2];                      // next gather: x_2
    }
    __syncthreads();  // B1(0): x_0, x_1 visible

    // prologue x-GEMM(0): acc = bias + x_0 @ Wx  (xbuf0)
#pragma unroll
    for (int rt = 0; rt < 2; ++rt) {
        acc[0][rt] = (f32x4){bi0, bi0, bi0, bi0};
        acc[1][rt] = (f32x4){bi1, bi1, bi1, bi1};
    }
    __builtin_amdgcn_s_setprio(1);
#pragma unroll
    for (int kt = 0; kt < 4; ++kt) {
        const int xo = off0 ^ (kt << 6);
#pragma unroll
        for (int rt = 0; rt < 2; ++rt) {
            short8 a = *(const short8*)(lds + rt * 4096 + xo);
            acc[0][rt] = __builtin_amdgcn_mfma_f32_16x16x32_bf16(a, bw[0][kt], acc[0][rt], 0, 0, 0);
            acc[1][rt] = __builtin_amdgcn_mfma_f32_16x16x32_bf16(a, bw[1][kt], acc[1][rt], 0, 0, 0);
        }
    }
    __builtin_amdgcn_s_setprio(0);

#pragma unroll 1
    for (int t = 0; t < KSEQ; ++t) {
        // ---------- interval A(t) ----------
        uint4 vnext;
        if (p == 0 && t <= 18) {   // gather x_{t+2} (t=18: own hp row for epilogue)
            vnext = *(const uint4*)((const unsigned char*)hp_bf + (size_t)gidx * 256 + l15 * 16);
            gidx = (t <= 16) ? aggrow[t + 3] : sgrow;
        }
        if (t > 0) {               // h-GEMM(t): acc += h_t @ Wh   (h_0 = 0 -> skip)
            __builtin_amdgcn_s_setprio(1);
#pragma unroll
            for (int kt = 0; kt < 4; ++kt) {
                const int ho = HBUF + (off0 ^ (kt << 6));
#pragma unroll
                for (int rt = 0; rt < 2; ++rt) {
                    short8 a = *(const short8*)(lds + rt * 4096 + ho);
                    acc[0][rt] = __builtin_amdgcn_mfma_f32_16x16x32_bf16(a, bw[0][kt + 4], acc[0][rt], 0, 0, 0);
                    acc[1][rt] = __builtin_amdgcn_mfma_f32_16x16x32_bf16(a, bw[1][kt + 4], acc[1][rt], 0, 0, 0);
                }
            }
            __builtin_amdgcn_s_setprio(0);
        }
        // gate activations
        if (p == 0) {
#pragma unroll
            for (int rt = 0; rt < 2; ++rt)
#pragma unroll
                for (int r = 0; r < 4; ++r) {
                    float av = sigx(acc[0][rt][r]) * tanhx(acc[1][rt][r]);
                    *(float*)(lds + sb0 + rt * 8192 + r * 2048) = av;
                }
        } else {
#pragma unroll
            for (int rt = 0; rt < 2; ++rt)
#pragma unroll
                for (int r = 0; r < 4; ++r) {
                    cst[rt][r] *= sigx(acc[0][rt][r]);   // fold sigma(f) now
                    so_[rt][r] = sigx(acc[1][rt][r]);
                }
        }
        __syncthreads();  // B2(t): sbuf(a) visible; xbuf/hbuf MFMA reads done

        // ---------- interval B(t) ----------
        if (t < KSEQ - 1) {        // x-GEMM(t+1) into reborn acc
            const int xrd = ((t + 1) & 1) << 13;
#pragma unroll
            for (int rt = 0; rt < 2; ++rt) {
                acc[0][rt] = (f32x4){bi0, bi0, bi0, bi0};
                acc[1][rt] = (f32x4){bi1, bi1, bi1, bi1};
            }
            __builtin_amdgcn_s_setprio(1);
#pragma unroll
            for (int kt = 0; kt < 4; ++kt) {
                const int xo = xrd + (off0 ^ (kt << 6));
#pragma unroll
                for (int rt = 0; rt < 2; ++rt) {
                    short8 a = *(const short8*)(lds + rt * 4096 + xo);
                    acc[0][rt] = __builtin_amdgcn_mfma_f32_16x16x32_bf16(a, bw[0][kt], acc[0][rt], 0, 0, 0);
                    acc[1][rt] = __builtin_amdgcn_mfma_f32_16x16x32_bf16(a, bw[1][kt], acc[1][rt], 0, 0, 0);
                }
            }
            __builtin_amdgcn_s_setprio(0);
        }
        if (p == 1) {
            // elementwise: c = cst + a; h -> hbuf (+ h_n/c_n at t=19)
#pragma unroll
            for (int rt = 0; rt < 2; ++rt)
#pragma unroll
                for (int r = 0; r < 4; ++r) {
                    float a = *(const float*)(lds + sb0 + rt * 8192 + r * 2048);
                    float c = cst[rt][r] + a;
                    cst[rt][r] = c;
                    float hv = so_[rt][r] * tanhx(c);
                    unsigned pk;
                    asm("v_cvt_pk_bf16_f32 %0, %1, %2" : "=v"(pk) : "v"(hv), "v"(hv));
                    int hoff = (hb0 + rt * 4096 + r * 256) ^ (hswz ^ (r << 4));
                    *(unsigned short*)(lds + hoff) = (unsigned short)pk;
                    if (t == KSEQ - 1) {
                        int row = rt * 16 + lq * 4 + r;
                        int grow = base + row;
                        if (grow < NN) {
                            out[HN_OFF + (size_t)grow * 128 + colj] = hv;
                            out[CN_OFF + (size_t)grow * 128 + colj] = c;
                        }
                    }
                }
        } else if (t <= 18) {
            *(uint4*)(lds + ((t & 1) << 13) + xw_off) = vnext;  // stage x_{t+2} / own hp
        }
        __syncthreads();  // B1(t+1): hbuf = h_{t+1}, staged x visible
    }
    // here: hbuf = h_20; xbuf0 = own hp rows (staged at t=18)

    // epilogue: out = elu([hp | h_n] @ W); all 16 waves, row-half rt = p
    short8 bo[8];
#pragma unroll
    for (int kt = 0; kt < 8; ++kt)
        bo[kt] = *(const short8*)((const unsigned char*)Wtt + colj * 512 + kt * 64 + lq * 16);

    f32x4 a2 = (f32x4){0.f, 0.f, 0.f, 0.f};
    const int ebase = p * 4096;
#pragma unroll
    for (int kt = 0; kt < 4; ++kt) {
        short8 a = *(const short8*)(lds + ebase + (off0 ^ (kt << 6)));           // hp (xbuf0)
        a2 = __builtin_amdgcn_mfma_f32_16x16x32_bf16(a, bo[kt], a2, 0, 0, 0);
    }
#pragma unroll
    for (int kt = 0; kt < 4; ++kt) {
        short8 a = *(const short8*)(lds + HBUF + ebase + (off0 ^ (kt << 6)));    // h_n (hbuf)
        a2 = __builtin_amdgcn_mfma_f32_16x16x32_bf16(a, bo[kt + 4], a2, 0, 0, 0);
    }
#pragma unroll
    for (int r = 0; r < 4; ++r) {
        int row = p * 16 + lq * 4 + r;
        int grow = base + row;
        if (grow < NN) {
            float v = a2[r];
            out[(size_t)grow * 128 + colj] = (v > 0.f) ? v : (exp2x(L2E * v) - 1.f);
        }
    }
}

extern "C" void kernel_launch(void* const* d_in, const int* in_sizes, int n_in,
                              void* d_out, int out_size, void* d_ws, size_t ws_size,
                              hipStream_t stream) {
    (void)in_sizes; (void)n_in; (void)out_size; (void)ws_size;
    const float* h   = (const float*)d_in[0];
    const int*   agg = (const int*)d_in[1];
    const float* Wp  = (const float*)d_in[2];
    const float* W   = (const float*)d_in[3];
    const float* Wih = (const float*)d_in[4];
    const float* Whh = (const float*)d_in[5];
    const float* bih = (const float*)d_in[6];
    const float* bhh = (const float*)d_in[7];
    float* out = (float*)d_out;

    unsigned short* hp_bf = (unsigned short*)d_ws;       // 50000*128 bf16
    unsigned short* Wih_b = hp_bf + 6400000;             // 512*128
    unsigned short* Whh_b = Wih_b + 65536;               // 512*128
    unsigned short* Wpt   = Whh_b + 65536;               // 128*256 (W_past^T)
    unsigned short* Wtt   = Wpt + 32768;                 // 128*256 (W^T)
    float*          bsum  = (float*)(Wtt + 32768);       // 512

    prep_kernel<<<771, 256, 0, stream>>>(Wp, W, Wih, Whh, bih, bhh, Wih_b, Whh_b, Wpt, Wtt, bsum);
    hp_kernel<<<1563, 512, 0, stream>>>(h, Wpt, hp_bf);
    lstm_kernel<<<1563, 1024, 0, stream>>>(hp_bf, agg, Wih_b, Whh_b, Wtt, bsum, out);
}

// Round 6
// 383.234 us; speedup vs baseline: 1.5148x; 1.4770x over previous
//
#include <hip/hip_runtime.h>

#define NN 50000
#define KSEQ 20
#define HN_OFF 6400000   // N*128
#define CN_OFF 12800000  // 2*N*128

using short8 = __attribute__((ext_vector_type(8))) short;
using f32x4  = __attribute__((ext_vector_type(4))) float;

__device__ __forceinline__ unsigned short f2bf(float f) {
    unsigned int u = __float_as_uint(f);
    return (unsigned short)((u + 0x7FFFu + ((u >> 16) & 1u)) >> 16);  // RNE
}
__device__ __forceinline__ float exp2x(float x) { float r; asm("v_exp_f32 %0, %1" : "=v"(r) : "v"(x)); return r; }
__device__ __forceinline__ float rcpx(float x)  { float r; asm("v_rcp_f32 %0, %1" : "=v"(r) : "v"(x)); return r; }

#define L2E 1.4426950408889634f
__device__ __forceinline__ float sigx(float x)  { return rcpx(1.f + exp2x(-L2E * x)); }
__device__ __forceinline__ float tanhx(float x) { return fmaf(-2.f, rcpx(1.f + exp2x((2.f * L2E) * x)), 1.f); }

// ---- prep: bf16 weight packs (+transposes) and bias sum ----
__global__ void prep_kernel(const float* __restrict__ Wp, const float* __restrict__ W,
                            const float* __restrict__ Wih, const float* __restrict__ Whh,
                            const float* __restrict__ bih, const float* __restrict__ bhh,
                            unsigned short* __restrict__ Wih_b, unsigned short* __restrict__ Whh_b,
                            unsigned short* __restrict__ Wpt, unsigned short* __restrict__ Wtt,
                            float* __restrict__ bsum) {
    int tid = blockIdx.x * blockDim.x + threadIdx.x;
    if (tid < 65536) { Wih_b[tid] = f2bf(Wih[tid]); return; }
    tid -= 65536;
    if (tid < 65536) { Whh_b[tid] = f2bf(Whh[tid]); return; }
    tid -= 65536;
    if (tid < 32768) { int j = tid >> 8, k = tid & 255; Wpt[tid] = f2bf(Wp[k * 128 + j]); return; }
    tid -= 32768;
    if (tid < 32768) { int j = tid >> 8, k = tid & 255; Wtt[tid] = f2bf(W[k * 128 + j]); return; }
    tid -= 32768;
    if (tid < 512) { bsum[tid] = bih[tid] + bhh[tid]; }
}

// ---- K1: hp = bf16(h @ W_past), 32 rows/block, 8 waves (16 cols each) ----
__global__ __launch_bounds__(512, 2) void hp_kernel(const float* __restrict__ h,
                                                    const unsigned short* __restrict__ Wpt,
                                                    unsigned short* __restrict__ hp_bf) {
    __shared__ __align__(16) unsigned char smem[32 * 512];
    const int tid = threadIdx.x;
    const int w = tid >> 6, l = tid & 63;
    const int l15 = l & 15, lq = l >> 4;
    const int base = blockIdx.x * 32;

#pragma unroll
    for (int i = 0; i < 4; ++i) {
        int chunk = tid + 512 * i;
        int row = chunk >> 6, kc = chunk & 63;
        int grow = base + row;
        float4 v = make_float4(0.f, 0.f, 0.f, 0.f);
        if (grow < NN) v = *(const float4*)(h + (size_t)grow * 256 + kc * 4);
        ushort4 bv = make_ushort4(f2bf(v.x), f2bf(v.y), f2bf(v.z), f2bf(v.w));
        int off = (row * 512 + kc * 8) ^ ((row & 7) << 4);
        *(ushort4*)(smem + off) = bv;
    }
    __syncthreads();

    const int jb = w * 16 + l15;
    short8 bf[8];
#pragma unroll
    for (int kt = 0; kt < 8; ++kt)
        bf[kt] = *(const short8*)((const unsigned char*)Wpt + jb * 512 + kt * 64 + lq * 16);

    f32x4 acc[2];
    acc[0] = (f32x4){0.f, 0.f, 0.f, 0.f};
    acc[1] = (f32x4){0.f, 0.f, 0.f, 0.f};
#pragma unroll
    for (int kt = 0; kt < 8; ++kt) {
#pragma unroll
        for (int rt = 0; rt < 2; ++rt) {
            int arow = rt * 16 + l15;
            int off = (arow * 512 + kt * 64 + lq * 16) ^ ((arow & 7) << 4);
            short8 a = *(const short8*)(smem + off);
            acc[rt] = __builtin_amdgcn_mfma_f32_16x16x32_bf16(a, bf[kt], acc[rt], 0, 0, 0);
        }
    }
#pragma unroll
    for (int rt = 0; rt < 2; ++rt)
#pragma unroll
        for (int r = 0; r < 4; ++r) {
            int row = rt * 16 + lq * 4 + r;
            int grow = base + row;
            if (grow < NN) hp_bf[(size_t)grow * 128 + w * 16 + l15] = f2bf(acc[rt][r]);
        }
}

// ---- K2: 8-wave, wave-self-contained LSTM. 32 rows/block = 2 groups of 16.
// Wave w owns ALL 4 gates for cols w*16..w*16+15 (bw = 128 regs, no exchange).
// Phase X(t): MFMA gates A(t) || update_B(t-1) VALU || stage x_B(t+1)
// Phase Y(t): MFMA gates B(t) || update_A(t)  VALU || stage x_A(t+2)
// LDS (24KB): xbufA[2] @0/@4096, xbufB[2] @8192/@12288, hbufA @16384, hbufB @20480
#define XA0 0
#define XA1 4096
#define XB0 8192
#define XB1 12288
#define HBA 16384
#define HBB 20480

__global__ __launch_bounds__(512, 2) void lstm_kernel(const unsigned short* __restrict__ hp_bf,
                                                      const int* __restrict__ agg,
                                                      const unsigned short* __restrict__ Wih_b,
                                                      const unsigned short* __restrict__ Whh_b,
                                                      const unsigned short* __restrict__ Wtt,
                                                      const float* __restrict__ bsum,
                                                      float* __restrict__ out) {
    __shared__ __align__(16) unsigned char lds[24576];
    const int tid = threadIdx.x;
    const int w = tid >> 6, l = tid & 63;
    const int l15 = l & 15, lq = l >> 4;
    const int base = blockIdx.x * 32;
    const int colj = w * 16 + l15;
    const int sgB = w >> 2;                 // 0: stages group A, 1: stages group B

    // weights: 4 gates x 8 k-tiles (0..3: W_ih/x, 4..7: W_hh/h); 128 regs -> AGPR
    short8 bw[4][8];
    float bi[4];
#pragma unroll
    for (int g = 0; g < 4; ++g) {
        const int j = g * 128 + colj;
#pragma unroll
        for (int kt = 0; kt < 4; ++kt) {
            bw[g][kt]     = *(const short8*)((const unsigned char*)Wih_b + j * 256 + kt * 64 + lq * 16);
            bw[g][kt + 4] = *(const short8*)((const unsigned char*)Whh_b + j * 256 + kt * 64 + lq * 16);
        }
        bi[g] = bsum[j];
    }

    // A-frag base offset within a 4KB (16x128 bf16) buffer; kt XORs (kt<<6)
    const int off0 = (l15 * 256 + lq * 16) ^ ((l15 & 7) << 4);

    // staging: lane handles (group row srow, 16B chunk l15) of its group's x-tile
    const int srow = (w & 3) * 4 + lq;
    const int grow_nom = base + sgB * 16 + srow;
    const int sgrow = grow_nom < NN ? grow_nom : NN - 1;
    const int* aggrow = agg + (size_t)sgrow * KSEQ;
    const int xw_off = (srow * 256 + l15 * 16) ^ ((srow & 7) << 4);

    // h-write base: row16 = lq*4+e, col colj; addr = hb + (row16*256+colj*2)^((row16&7)<<4)
    const int hb0 = (lq * 4 * 256 + colj * 2) ^ ((lq & 1) << 6);

    f32x4 cstA = (f32x4){0.f, 0.f, 0.f, 0.f};
    f32x4 cstB = (f32x4){0.f, 0.f, 0.f, 0.f};
    f32x4 accA[4], accB[4];

    // prologue: stage x(0), x(1) for own group
    {
        int i0 = aggrow[0], i1 = aggrow[1];
        uint4 v0 = *(const uint4*)((const unsigned char*)hp_bf + (size_t)i0 * 256 + l15 * 16);
        uint4 v1 = *(const uint4*)((const unsigned char*)hp_bf + (size_t)i1 * 256 + l15 * 16);
        const int gb = sgB * 8192;
        *(uint4*)(lds + gb + xw_off) = v0;
        *(uint4*)(lds + gb + 4096 + xw_off) = v1;
    }
    __syncthreads();

#pragma unroll 1
    for (int t = 0; t < KSEQ; ++t) {
        const int xApar = (t & 1) ? XA1 : XA0;
        const int xBpar = (t & 1) ? XB1 : XB0;

        // ================= phase X(t) =================
        uint4 vB;
        if (sgB == 1 && t >= 1) {          // gather x_B(t+1) (t=19: own hp row)
            int idx = (t <= 18) ? aggrow[t + 1] : sgrow;
            vB = *(const uint4*)((const unsigned char*)hp_bf + (size_t)idx * 256 + l15 * 16);
        }
        // MFMA_A(t)
#pragma unroll
        for (int g = 0; g < 4; ++g) accA[g] = (f32x4){bi[g], bi[g], bi[g], bi[g]};
#pragma unroll
        for (int kt = 0; kt < 4; ++kt) {
            short8 a = *(const short8*)(lds + xApar + (off0 ^ (kt << 6)));
#pragma unroll
            for (int g = 0; g < 4; ++g)
                accA[g] = __builtin_amdgcn_mfma_f32_16x16x32_bf16(a, bw[g][kt], accA[g], 0, 0, 0);
        }
        if (t > 0) {
#pragma unroll
            for (int kt = 0; kt < 4; ++kt) {
                short8 a = *(const short8*)(lds + HBA + (off0 ^ (kt << 6)));
#pragma unroll
                for (int g = 0; g < 4; ++g)
                    accA[g] = __builtin_amdgcn_mfma_f32_16x16x32_bf16(a, bw[g][kt + 4], accA[g], 0, 0, 0);
            }
            // update_B(t-1): fully wave-local (overlaps MFMA_A on the other pipe)
#pragma unroll
            for (int e = 0; e < 4; ++e) {
                float c = fmaf(sigx(accB[1][e]), cstB[e], sigx(accB[0][e]) * tanhx(accB[2][e]));
                cstB[e] = c;
                float hv = sigx(accB[3][e]) * tanhx(c);
                unsigned pk;
                asm("v_cvt_pk_bf16_f32 %0, %1, %2" : "=v"(pk) : "v"(hv), "v"(hv));
                *(unsigned short*)(lds + HBB + ((hb0 + e * 256) ^ (e << 4))) = (unsigned short)pk;
            }
        }
        if (sgB == 1 && t >= 1)
            *(uint4*)(lds + (((t + 1) & 1) ? XB1 : XB0) + xw_off) = vB;
        __syncthreads();

        // ================= phase Y(t) =================
        uint4 vA;
        if (sgB == 0 && t <= 18) {          // gather x_A(t+2) (t=18: own hp row)
            int idx = (t <= 17) ? aggrow[t + 2] : sgrow;
            vA = *(const uint4*)((const unsigned char*)hp_bf + (size_t)idx * 256 + l15 * 16);
        }
        // MFMA_B(t)
#pragma unroll
        for (int g = 0; g < 4; ++g) accB[g] = (f32x4){bi[g], bi[g], bi[g], bi[g]};
#pragma unroll
        for (int kt = 0; kt < 4; ++kt) {
            short8 a = *(const short8*)(lds + xBpar + (off0 ^ (kt << 6)));
#pragma unroll
            for (int g = 0; g < 4; ++g)
                accB[g] = __builtin_amdgcn_mfma_f32_16x16x32_bf16(a, bw[g][kt], accB[g], 0, 0, 0);
        }
        if (t > 0) {
#pragma unroll
            for (int kt = 0; kt < 4; ++kt) {
                short8 a = *(const short8*)(lds + HBB + (off0 ^ (kt << 6)));
#pragma unroll
                for (int g = 0; g < 4; ++g)
                    accB[g] = __builtin_amdgcn_mfma_f32_16x16x32_bf16(a, bw[g][kt + 4], accB[g], 0, 0, 0);
            }
        }
        // update_A(t)
#pragma unroll
        for (int e = 0; e < 4; ++e) {
            float c = fmaf(sigx(accA[1][e]), cstA[e], sigx(accA[0][e]) * tanhx(accA[2][e]));
            cstA[e] = c;
            float hv = sigx(accA[3][e]) * tanhx(c);
            unsigned pk;
            asm("v_cvt_pk_bf16_f32 %0, %1, %2" : "=v"(pk) : "v"(hv), "v"(hv));
            *(unsigned short*)(lds + HBA + ((hb0 + e * 256) ^ (e << 4))) = (unsigned short)pk;
            if (t == KSEQ - 1) {
                int grow = base + lq * 4 + e;          // A rows always < NN
                out[HN_OFF + (size_t)grow * 128 + colj] = hv;
                out[CN_OFF + (size_t)grow * 128 + colj] = c;
            }
        }
        if (sgB == 0 && t <= 18)
            *(uint4*)(lds + ((t & 1) ? XA1 : XA0) + xw_off) = vA;
        __syncthreads();
    }

    // epilogue: update_B(19) -> hbufB + global h_n/c_n for B rows
#pragma unroll
    for (int e = 0; e < 4; ++e) {
        float c = fmaf(sigx(accB[1][e]), cstB[e], sigx(accB[0][e]) * tanhx(accB[2][e]));
        float hv = sigx(accB[3][e]) * tanhx(c);
        unsigned pk;
        asm("v_cvt_pk_bf16_f32 %0, %1, %2" : "=v"(pk) : "v"(hv), "v"(hv));
        *(unsigned short*)(lds + HBB + ((hb0 + e * 256) ^ (e << 4))) = (unsigned short)pk;
        int grow = base + 16 + lq * 4 + e;
        if (grow < NN) {
            out[HN_OFF + (size_t)grow * 128 + colj] = hv;
            out[CN_OFF + (size_t)grow * 128 + colj] = c;
        }
    }
    __syncthreads();  // hbufB/hbufA/xbufA[0]/xbufB[0] all final

    // out = elu([hp | h_n] @ W): wave w covers out-cols colj; groups A,B as row-halves
    short8 bo[8];
#pragma unroll
    for (int kt = 0; kt < 8; ++kt)
        bo[kt] = *(const short8*)((const unsigned char*)Wtt + colj * 512 + kt * 64 + lq * 16);

    f32x4 a2A = (f32x4){0.f, 0.f, 0.f, 0.f};
    f32x4 a2B = (f32x4){0.f, 0.f, 0.f, 0.f};
#pragma unroll
    for (int kt = 0; kt < 4; ++kt) {
        const int o = off0 ^ (kt << 6);
        short8 aA = *(const short8*)(lds + XA0 + o);    // own hp rows (A)
        short8 aB = *(const short8*)(lds + XB0 + o);    // own hp rows (B)
        a2A = __builtin_amdgcn_mfma_f32_16x16x32_bf16(aA, bo[kt], a2A, 0, 0, 0);
        a2B = __builtin_amdgcn_mfma_f32_16x16x32_bf16(aB, bo[kt], a2B, 0, 0, 0);
    }
#pragma unroll
    for (int kt = 0; kt < 4; ++kt) {
        const int o = off0 ^ (kt << 6);
        short8 aA = *(const short8*)(lds + HBA + o);    // h_n (A)
        short8 aB = *(const short8*)(lds + HBB + o);    // h_n (B)
        a2A = __builtin_amdgcn_mfma_f32_16x16x32_bf16(aA, bo[kt + 4], a2A, 0, 0, 0);
        a2B = __builtin_amdgcn_mfma_f32_16x16x32_bf16(aB, bo[kt + 4], a2B, 0, 0, 0);
    }
#pragma unroll
    for (int e = 0; e < 4; ++e) {
        int rowA = base + lq * 4 + e;
        int rowB = rowA + 16;
        float vA = a2A[e], vB = a2B[e];
        out[(size_t)rowA * 128 + colj] = (vA > 0.f) ? vA : (exp2x(L2E * vA) - 1.f);
        if (rowB < NN)
            out[(size_t)rowB * 128 + colj] = (vB > 0.f) ? vB : (exp2x(L2E * vB) - 1.f);
    }
}

extern "C" void kernel_launch(void* const* d_in, const int* in_sizes, int n_in,
                              void* d_out, int out_size, void* d_ws, size_t ws_size,
                              hipStream_t stream) {
    (void)in_sizes; (void)n_in; (void)out_size; (void)ws_size;
    const float* h   = (const float*)d_in[0];
    const int*   agg = (const int*)d_in[1];
    const float* Wp  = (const float*)d_in[2];
    const float* W   = (const float*)d_in[3];
    const float* Wih = (const float*)d_in[4];
    const float* Whh = (const float*)d_in[5];
    const float* bih = (const float*)d_in[6];
    const float* bhh = (const float*)d_in[7];
    float* out = (float*)d_out;

    unsigned short* hp_bf = (unsigned short*)d_ws;       // 50000*128 bf16
    unsigned short* Wih_b = hp_bf + 6400000;             // 512*128
    unsigned short* Whh_b = Wih_b + 65536;               // 512*128
    unsigned short* Wpt   = Whh_b + 65536;               // 128*256 (W_past^T)
    unsigned short* Wtt   = Wpt + 32768;                 // 128*256 (W^T)
    float*          bsum  = (float*)(Wtt + 32768);       // 512

    prep_kernel<<<771, 256, 0, stream>>>(Wp, W, Wih, Whh, bih, bhh, Wih_b, Whh_b, Wpt, Wtt, bsum);
    hp_kernel<<<1563, 512, 0, stream>>>(h, Wpt, hp_bf);
    lstm_kernel<<<1563, 512, 0, stream>>>(hp_bf, agg, Wih_b, Whh_b, Wtt, bsum, out);
}